// Round 3
// baseline (263.560 us; speedup 1.0000x reference)
//
#include <hip/hip_runtime.h>
#include <cstdint>

#define LT 24
#define NSITE (LT*LT*LT*LT)      // 331776
#define HALF  (NSITE/2)          // 165888
#define NCOMPLEX (4*NSITE*9)     // 11943936 complex elements total

typedef float vf4 __attribute__((ext_vector_type(4)));   // native vector for nontemporal builtins

struct C3 { float re[9]; float im[9]; };

// 9 contiguous floats, base only guaranteed 4B-aligned.
__device__ __forceinline__ void load9(float* d, const float* __restrict__ p) {
    float4 a, b;
    __builtin_memcpy(&a, p,     16);
    __builtin_memcpy(&b, p + 4, 16);
    d[0]=a.x; d[1]=a.y; d[2]=a.z; d[3]=a.w;
    d[4]=b.x; d[5]=b.y; d[6]=b.z; d[7]=b.w;
    d[8]=p[8];
}

__device__ __forceinline__ void loadM(C3& m, const float* __restrict__ re,
                                      const float* __restrict__ im, int off) {
    load9(m.re, re + off);
    load9(m.im, im + off);
}

// store matrix as interleaved (re,im) pairs at complex-element base cbase.
__device__ __forceinline__ void storeM(float2* __restrict__ out, int cbase, const C3& m) {
    float4 v;
    v.x=m.re[0]; v.y=m.im[0]; v.z=m.re[1]; v.w=m.im[1];
    __builtin_memcpy(out + cbase,     &v, 16);
    v.x=m.re[2]; v.y=m.im[2]; v.z=m.re[3]; v.w=m.im[3];
    __builtin_memcpy(out + cbase + 2, &v, 16);
    v.x=m.re[4]; v.y=m.im[4]; v.z=m.re[5]; v.w=m.im[5];
    __builtin_memcpy(out + cbase + 4, &v, 16);
    v.x=m.re[6]; v.y=m.im[6]; v.z=m.re[7]; v.w=m.im[7];
    __builtin_memcpy(out + cbase + 6, &v, 16);
    float2 w; w.x=m.re[8]; w.y=m.im[8];
    out[cbase + 8] = w;
}

// 18-float contiguous workspace record (re[0..8], im[0..8]); 8B-aligned base.
__device__ __forceinline__ void store18(float* __restrict__ p, const C3& m) {
    float4 v;
    v.x=m.re[0]; v.y=m.re[1]; v.z=m.re[2]; v.w=m.re[3];
    __builtin_memcpy(p,      &v, 16);
    v.x=m.re[4]; v.y=m.re[5]; v.z=m.re[6]; v.w=m.re[7];
    __builtin_memcpy(p + 4,  &v, 16);
    v.x=m.re[8]; v.y=m.im[0]; v.z=m.im[1]; v.w=m.im[2];
    __builtin_memcpy(p + 8,  &v, 16);
    v.x=m.im[3]; v.y=m.im[4]; v.z=m.im[5]; v.w=m.im[6];
    __builtin_memcpy(p + 12, &v, 16);
    float2 w; w.x=m.im[7]; w.y=m.im[8];
    __builtin_memcpy(p + 16, &w, 8);
}

__device__ __forceinline__ void load18(C3& m, const float* __restrict__ p) {
    float4 a;
    __builtin_memcpy(&a, p,      16); m.re[0]=a.x; m.re[1]=a.y; m.re[2]=a.z; m.re[3]=a.w;
    __builtin_memcpy(&a, p + 4,  16); m.re[4]=a.x; m.re[5]=a.y; m.re[6]=a.z; m.re[7]=a.w;
    __builtin_memcpy(&a, p + 8,  16); m.re[8]=a.x; m.im[0]=a.y; m.im[1]=a.z; m.im[2]=a.w;
    __builtin_memcpy(&a, p + 12, 16); m.im[3]=a.x; m.im[4]=a.y; m.im[5]=a.z; m.im[6]=a.w;
    float2 w; __builtin_memcpy(&w, p + 16, 8); m.im[7]=w.x; m.im[8]=w.y;
}

// o = a @ b
__device__ __forceinline__ void mmul(C3& o, const C3& a, const C3& b) {
#pragma unroll
    for (int r = 0; r < 3; ++r) {
#pragma unroll
        for (int c = 0; c < 3; ++c) {
            float sr = 0.f, si = 0.f;
#pragma unroll
            for (int k = 0; k < 3; ++k) {
                float ar = a.re[r*3+k], ai = a.im[r*3+k];
                float br = b.re[k*3+c], bi = b.im[k*3+c];
                sr += ar*br - ai*bi;
                si += ar*bi + ai*br;
            }
            o.re[r*3+c] = sr; o.im[r*3+c] = si;
        }
    }
}

// f += cr * (a @ b)
__device__ __forceinline__ void mmul_acc(C3& f, const C3& a, const C3& b, float cr) {
#pragma unroll
    for (int r = 0; r < 3; ++r) {
#pragma unroll
        for (int c = 0; c < 3; ++c) {
            float sr = 0.f, si = 0.f;
#pragma unroll
            for (int k = 0; k < 3; ++k) {
                float ar = a.re[r*3+k], ai = a.im[r*3+k];
                float br = b.re[k*3+c], bi = b.im[k*3+c];
                sr += ar*br - ai*bi;
                si += ar*bi + ai*br;
            }
            f.re[r*3+c] += cr * sr; f.im[r*3+c] += cr * si;
        }
    }
}

// o = a @ b^dagger
__device__ __forceinline__ void mmul_adjB(C3& o, const C3& a, const C3& b) {
#pragma unroll
    for (int r = 0; r < 3; ++r) {
#pragma unroll
        for (int c = 0; c < 3; ++c) {
            float sr = 0.f, si = 0.f;
#pragma unroll
            for (int k = 0; k < 3; ++k) {
                float ar = a.re[r*3+k], ai = a.im[r*3+k];
                float br = b.re[c*3+k], bi = b.im[c*3+k];
                sr += ar*br + ai*bi;
                si += ai*br - ar*bi;
            }
            o.re[r*3+c] = sr; o.im[r*3+c] = si;
        }
    }
}

// o = a^dagger @ b
__device__ __forceinline__ void madjA_mul(C3& o, const C3& a, const C3& b) {
#pragma unroll
    for (int r = 0; r < 3; ++r) {
#pragma unroll
        for (int c = 0; c < 3; ++c) {
            float sr = 0.f, si = 0.f;
#pragma unroll
            for (int k = 0; k < 3; ++k) {
                float ar = a.re[k*3+r], ai = a.im[k*3+r];
                float br = b.re[k*3+c], bi = b.im[k*3+c];
                sr += ar*br + ai*bi;
                si += ar*bi - ai*br;
            }
            o.re[r*3+c] = sr; o.im[r*3+c] = si;
        }
    }
}

// idx in [0, HALF) -> site of given parity (0=even updated subset, 1=odd)
__device__ __forceinline__ int site_from_idx(int idx, int parity,
                                             int& t, int& z, int& y, int& x) {
    int xh = idx % 12;  int r = idx / 12;
    y = r % LT; r /= LT;
    z = r % LT; t = r / LT;
    x = 2 * xh + ((t + z + y + parity) & 1);
    return ((t * LT + z) * LT + y) * LT + x;
}

// ---- Kernel A: planar -> interleaved streaming copy of the WHOLE tensor ----
// Coalesced float4 loads; non-temporal stores (output never re-read except the
// 12 MB dir-0-even slice -> avoid polluting L3, keep x resident for kernel B).
__global__ __launch_bounds__(256)
void interleave_copy(const float* __restrict__ xre, const float* __restrict__ xim,
                     vf4* __restrict__ out) {
    const vf4* __restrict__ re4 = (const vf4*)xre;
    const vf4* __restrict__ im4 = (const vf4*)xim;
    const int nquad  = NCOMPLEX / 4;          // 2985984
    const int stride = gridDim.x * blockDim.x;
    for (int q = blockIdx.x * blockDim.x + threadIdx.x; q < nquad; q += stride) {
        vf4 r = re4[q];
        vf4 i = im4[q];
        vf4 o0 = { r.x, i.x, r.y, i.y };
        vf4 o1 = { r.z, i.z, r.w, i.w };
        __builtin_nontemporal_store(o0, out + 2*q);
        __builtin_nontemporal_store(o1, out + 2*q + 1);
    }
}

// ---- Kernel B1: staple partials, one thread per (even site, nu) ------------
// 3x the threads of the monolith (7.6 waves/SIMD demand) and a small body
// (~6 matrix loads, 4 mmuls) -> low VGPR -> real latency hiding.
// Writes per-nu partial f (72 B contiguous per thread) to workspace.
__global__ __launch_bounds__(256)
void stout_staples(const float* __restrict__ xre, const float* __restrict__ xim,
                   const float* __restrict__ coeff, float* __restrict__ ws) {
    const int gid = blockIdx.x * 256 + threadIdx.x;
    const int i   = gid / HALF;          // 0..2 = nu-1, uniform per block
    const int idx = gid - i * HALF;
    const int d   = i + 1;

    int t, z, y, x;
    const int s = site_from_idx(idx, 0, t, z, y, x);

    const float c2  = 0.07957747154594768f * atanf(coeff[2*i]);
    const float c2p = 0.07957747154594768f * atanf(coeff[2*i + 1]);

    const int tp = (t + 1 < LT) ? t + 1 : 0;
    const int stt = ((tp * LT + z) * LT + y) * LT + x;    // s + T^

    int sp, sm, smt;  // s+nu, s-nu, s-nu+T  (branch is block-uniform)
    if (i == 0) {
        const int zp = (z + 1 < LT) ? z + 1 : 0;
        const int zm = (z > 0) ? z - 1 : LT - 1;
        sp  = ((t  * LT + zp) * LT + y) * LT + x;
        sm  = ((t  * LT + zm) * LT + y) * LT + x;
        smt = ((tp * LT + zm) * LT + y) * LT + x;
    } else if (i == 1) {
        const int yp = (y + 1 < LT) ? y + 1 : 0;
        const int ym = (y > 0) ? y - 1 : LT - 1;
        sp  = ((t  * LT + z) * LT + yp) * LT + x;
        sm  = ((t  * LT + z) * LT + ym) * LT + x;
        smt = ((tp * LT + z) * LT + ym) * LT + x;
    } else {
        const int xp = (x + 1 < LT) ? x + 1 : 0;
        const int xm = (x > 0) ? x - 1 : LT - 1;
        sp  = ((t  * LT + z) * LT + y) * LT + xp;
        sm  = ((t  * LT + z) * LT + y) * LT + xm;
        smt = ((tp * LT + z) * LT + y) * LT + xm;
    }

    C3 A, B, Cm, tmp, pf;
#pragma unroll
    for (int j = 0; j < 9; ++j) { pf.re[j] = 0.f; pf.im[j] = 0.f; }

    // forward staple: x[nu](s) @ (x0(s+nu) @ x[nu](s+T)^dag)
    loadM(B,  xre, xim, sp * 9);                  // dir 0, odd neighbor
    loadM(Cm, xre, xim, (d * NSITE + stt) * 9);
    mmul_adjB(tmp, B, Cm);
    loadM(A, xre, xim, (d * NSITE + s) * 9);
    mmul_acc(pf, A, tmp, c2);

    // backward staple: (x[nu](s-nu)^dag @ x0(s-nu)) @ x[nu](s-nu+T)
    loadM(A, xre, xim, (d * NSITE + sm) * 9);
    loadM(B, xre, xim, sm * 9);                   // dir 0, odd neighbor
    madjA_mul(tmp, A, B);
    loadM(Cm, xre, xim, (d * NSITE + smt) * 9);
    mmul_acc(pf, tmp, Cm, c2p);

    store18(ws + (size_t)(i * HALF + idx) * 18, pf);
}

// ---- Kernel B2: reduce partials + matexp + store updated dir-0 even link ---
__global__ __launch_bounds__(256)
void stout_exp(const float* __restrict__ xre, const float* __restrict__ xim,
               const float* __restrict__ ws, float2* __restrict__ out) {
    const int idx = blockIdx.x * 256 + threadIdx.x;

    int t, z, y, x;
    const int s = site_from_idx(idx, 0, t, z, y, x);

    C3 f, p;
    load18(f, ws + (size_t)idx * 18);
    load18(p, ws + (size_t)(HALF + idx) * 18);
#pragma unroll
    for (int j = 0; j < 9; ++j) { f.re[j] += p.re[j]; f.im[j] += p.im[j]; }
    load18(p, ws + (size_t)(2 * HALF + idx) * 18);
#pragma unroll
    for (int j = 0; j < 9; ++j) { f.re[j] += p.re[j]; f.im[j] += p.im[j]; }

    C3 U;
    loadM(U, xre, xim, s * 9);

    // M = f @ U^dag ; A = 0.5(M - M^dag) ; Zt = A - tr(A)/3 * I
    C3 Mm;
    mmul_adjB(Mm, f, U);
    C3 Zt;
#pragma unroll
    for (int r = 0; r < 3; ++r) {
#pragma unroll
        for (int cq = 0; cq < 3; ++cq) {
            Zt.re[r*3+cq] = 0.5f * (Mm.re[r*3+cq] - Mm.re[cq*3+r]);
            Zt.im[r*3+cq] = 0.5f * (Mm.im[r*3+cq] + Mm.im[cq*3+r]);
        }
    }
    float trIm = (Zt.im[0] + Zt.im[4] + Zt.im[8]) / 3.0f;
    Zt.im[0] -= trIm; Zt.im[4] -= trIm; Zt.im[8] -= trIm;

    // matexp: scale by 0.5^4, 12-term Horner, 4 squarings
#pragma unroll
    for (int j = 0; j < 9; ++j) { Zt.re[j] *= 0.0625f; Zt.im[j] *= 0.0625f; }

    C3 E;
#pragma unroll
    for (int j = 0; j < 9; ++j) { E.re[j] = 0.f; E.im[j] = 0.f; }
    E.re[0] = 1.f; E.re[4] = 1.f; E.re[8] = 1.f;

    C3 Tm;
#pragma unroll
    for (int k = 12; k >= 1; --k) {
        mmul(Tm, Zt, E);
        const float invk = 1.0f / (float)k;
#pragma unroll
        for (int j = 0; j < 9; ++j) {
            E.re[j] = Tm.re[j] * invk;
            E.im[j] = Tm.im[j] * invk;
        }
        E.re[0] += 1.f; E.re[4] += 1.f; E.re[8] += 1.f;
    }
#pragma unroll
    for (int q = 0; q < 4; ++q) {
        mmul(Tm, E, E);
        E = Tm;
    }

    // ymu = E @ U  (even site: xmu_fix = 0)
    C3 Y;
    mmul(Y, E, U);
    storeM(out, s * 9, Y);
}

// ---- Fallback monolith (used only if workspace is too small) ---------------
__global__ __launch_bounds__(256)
void stout_update(const float* __restrict__ xre, const float* __restrict__ xim,
                  const float* __restrict__ coeff, float2* __restrict__ out) {
    const int idx = blockIdx.x * 256 + threadIdx.x;

    int t, z, y, x;
    const int s = site_from_idx(idx, 0, t, z, y, x);

    float c[6];
#pragma unroll
    for (int i = 0; i < 6; ++i)
        c[i] = 0.07957747154594768f * atanf(coeff[i]);

    int tp = (t + 1 < LT) ? t + 1 : 0;
    int zp = (z + 1 < LT) ? z + 1 : 0;  int zm = (z > 0) ? z - 1 : LT - 1;
    int yp = (y + 1 < LT) ? y + 1 : 0;  int ym = (y > 0) ? y - 1 : LT - 1;
    int xp = (x + 1 < LT) ? x + 1 : 0;  int xm = (x > 0) ? x - 1 : LT - 1;

    const int stt = ((tp * LT + z) * LT + y) * LT + x;
    const int spv[3]  = { ((t  * LT + zp) * LT + y ) * LT + x,
                          ((t  * LT + z ) * LT + yp) * LT + x,
                          ((t  * LT + z ) * LT + y ) * LT + xp };
    const int smv[3]  = { ((t  * LT + zm) * LT + y ) * LT + x,
                          ((t  * LT + z ) * LT + ym) * LT + x,
                          ((t  * LT + z ) * LT + y ) * LT + xm };
    const int smtv[3] = { ((tp * LT + zm) * LT + y ) * LT + x,
                          ((tp * LT + z ) * LT + ym) * LT + x,
                          ((tp * LT + z ) * LT + y ) * LT + xm };

    C3 f;
#pragma unroll
    for (int j = 0; j < 9; ++j) { f.re[j] = 0.f; f.im[j] = 0.f; }

    C3 A, B, Cm, tmp;
#pragma unroll
    for (int i = 0; i < 3; ++i) {
        const int d = i + 1;
        loadM(A, xre, xim, (d * NSITE + s) * 9);
        loadM(B,  xre, xim, (     spv[i])        * 9);
        loadM(Cm, xre, xim, (d * NSITE + stt)    * 9);
        mmul_adjB(tmp, B, Cm);
        mmul_acc(f, A, tmp, c[2 * i]);
        loadM(A,  xre, xim, (d * NSITE + smv[i]) * 9);
        loadM(B,  xre, xim, (     smv[i])        * 9);
        madjA_mul(tmp, A, B);
        loadM(Cm, xre, xim, (d * NSITE + smtv[i])* 9);
        mmul_acc(f, tmp, Cm, c[2 * i + 1]);
    }

    C3 U;
    loadM(U, xre, xim, s * 9);

    C3 Mm;
    mmul_adjB(Mm, f, U);
    C3 Zt;
#pragma unroll
    for (int r = 0; r < 3; ++r) {
#pragma unroll
        for (int cq = 0; cq < 3; ++cq) {
            Zt.re[r*3+cq] = 0.5f * (Mm.re[r*3+cq] - Mm.re[cq*3+r]);
            Zt.im[r*3+cq] = 0.5f * (Mm.im[r*3+cq] + Mm.im[cq*3+r]);
        }
    }
    float trIm = (Zt.im[0] + Zt.im[4] + Zt.im[8]) / 3.0f;
    Zt.im[0] -= trIm; Zt.im[4] -= trIm; Zt.im[8] -= trIm;

#pragma unroll
    for (int j = 0; j < 9; ++j) { Zt.re[j] *= 0.0625f; Zt.im[j] *= 0.0625f; }

    C3 E;
#pragma unroll
    for (int j = 0; j < 9; ++j) { E.re[j] = 0.f; E.im[j] = 0.f; }
    E.re[0] = 1.f; E.re[4] = 1.f; E.re[8] = 1.f;

    C3 Tm;
#pragma unroll
    for (int k = 12; k >= 1; --k) {
        mmul(Tm, Zt, E);
        const float invk = 1.0f / (float)k;
#pragma unroll
        for (int j = 0; j < 9; ++j) {
            E.re[j] = Tm.re[j] * invk;
            E.im[j] = Tm.im[j] * invk;
        }
        E.re[0] += 1.f; E.re[4] += 1.f; E.re[8] += 1.f;
    }
#pragma unroll
    for (int q = 0; q < 4; ++q) {
        mmul(Tm, E, E);
        E = Tm;
    }

    C3 Y;
    mmul(Y, E, U);
    storeM(out, s * 9, Y);
}

extern "C" void kernel_launch(void* const* d_in, const int* in_sizes, int n_in,
                              void* d_out, int out_size, void* d_ws, size_t ws_size,
                              hipStream_t stream) {
    const float* xre   = (const float*)d_in[0];
    const float* xim   = (const float*)d_in[1];
    const float* coeff = (const float*)d_in[2];

    // Kernel A: coalesced planar->interleaved copy of all 4 dirs (191 MB traffic)
    interleave_copy<<<4096, 256, 0, stream>>>(xre, xim, (vf4*)d_out);

    const size_t ws_needed = (size_t)3 * HALF * 18 * sizeof(float);   // 35.8 MB
    if (ws_size >= ws_needed && d_ws != nullptr) {
        // B1: staple partials, 3 threads/site -> 7.6 waves/SIMD demand
        stout_staples<<<(3 * HALF) / 256, 256, 0, stream>>>(
            xre, xim, coeff, (float*)d_ws);
        // B2: reduce + matexp + store dir-0 even links
        stout_exp<<<HALF / 256, 256, 0, stream>>>(
            xre, xim, (const float*)d_ws, (float2*)d_out);
    } else {
        // fallback: proven monolithic update
        stout_update<<<HALF / 256, 256, 0, stream>>>(xre, xim, coeff, (float2*)d_out);
    }
}